// Round 2
// baseline (13759.822 us; speedup 1.0000x reference)
//
#include <hip/hip_runtime.h>
#include <math.h>

// 2-layer LSTM, B=32 T=256 D=512 H=1024, gate order i,j,f,o, forget bias 1.0
// Structure:
//   ZX1 = x @ W1[0:512,:]          (one big GEMM, all timesteps)
//   256x lstm_step(layer1)         (recurrent GEMM h@Wh fused with gate math)
//   ZX2 = h1 @ W2[0:1024,:]        (one big GEMM)
//   256x lstm_step(layer2) -> d_out

#define HSZ 1024
#define GSZ 4096
#define TSZ 256
#define BSZ 32
#define DSZ 512

__device__ __forceinline__ float sigf(float x) { return 1.0f / (1.0f + __expf(-x)); }

// ---------------- fp32 SGEMM: C[M,N] = A[M,K] @ Bm[K,N] ----------------
// BM=BN=128, BK=16, 256 threads, 8x8 per thread.
__global__ __launch_bounds__(256)
void sgemm128(const float* __restrict__ A, const float* __restrict__ Bm,
              float* __restrict__ C, int M, int N, int K) {
  __shared__ float As[16][132];
  __shared__ float Bs[16][132];
  const int tid = threadIdx.x;
  const int m_base = blockIdx.y * 128;
  const int n_base = blockIdx.x * 128;
  const int tm = tid >> 4, tn = tid & 15;
  float acc[8][8];
#pragma unroll
  for (int i = 0; i < 8; ++i)
#pragma unroll
    for (int j = 0; j < 8; ++j) acc[i][j] = 0.0f;

  for (int kt = 0; kt < K; kt += 16) {
#pragma unroll
    for (int i = 0; i < 2; ++i) {
      int q = tid * 2 + i;
      // A tile: 128 rows x 16 k, float4 along K, store transposed
      int ar = q >> 2, akq = (q & 3) * 4;
      float4 av = *(const float4*)(A + (size_t)(m_base + ar) * K + kt + akq);
      As[akq + 0][ar] = av.x;
      As[akq + 1][ar] = av.y;
      As[akq + 2][ar] = av.z;
      As[akq + 3][ar] = av.w;
      // B tile: 16 k-rows x 128 n, float4 along N
      int bk = q >> 5, bnq = (q & 31) * 4;
      *(float4*)&Bs[bk][bnq] =
          *(const float4*)(Bm + (size_t)(kt + bk) * N + n_base + bnq);
    }
    __syncthreads();
#pragma unroll
    for (int k = 0; k < 16; ++k) {
      float a[8], b[8];
      *(float4*)&a[0] = *(const float4*)&As[k][tm * 8];
      *(float4*)&a[4] = *(const float4*)&As[k][tm * 8 + 4];
      *(float4*)&b[0] = *(const float4*)&Bs[k][tn * 8];
      *(float4*)&b[4] = *(const float4*)&Bs[k][tn * 8 + 4];
#pragma unroll
      for (int i = 0; i < 8; ++i)
#pragma unroll
        for (int j = 0; j < 8; ++j) acc[i][j] = fmaf(a[i], b[j], acc[i][j]);
    }
    __syncthreads();
  }
#pragma unroll
  for (int i = 0; i < 8; ++i) {
    float* cr = C + (size_t)(m_base + tm * 8 + i) * N + n_base + tn * 8;
    *(float4*)cr = make_float4(acc[i][0], acc[i][1], acc[i][2], acc[i][3]);
    *(float4*)(cr + 4) = make_float4(acc[i][4], acc[i][5], acc[i][6], acc[i][7]);
  }
}

// ---------------- fused recurrent step ----------------
// z[b, :] = zx[b, :] + bias + h_prev[b, :] @ Wh;  gates -> c, h_out
// Grid: 256 blocks = 64 j-groups x 4 b-groups. Block: 512 thr = 4 jq x 8 b x 16 ks.
// Each thread: 4 j-columns x 4 gates partial dot over K/16 = 64 k's; LDS tree reduce.
// NOTE: blocks sharing Wh columns (jg, jg+64, jg+128, jg+192) land on the same
// XCD under %8 round-robin -> Wh slice (~2MB/XCD/layer) stays L2-resident.
__global__ __launch_bounds__(512)
void lstm_step(const float* __restrict__ Wh,     // [1024][4096]
               const float* __restrict__ zx_t,   // + b*zx_bs + col
               long zx_bs,
               const float* __restrict__ hprev,  // + b*hp_bs + k
               long hp_bs,
               const float* __restrict__ bias,   // [4096]
               float* __restrict__ c,            // [32][1024]
               float* __restrict__ hout,         // + b*ho_bs + j
               long ho_bs) {
  __shared__ float red[512][17];
  const int tid = threadIdx.x;
  const int jq = tid & 3;
  const int bl = (tid >> 2) & 7;
  const int ks = tid >> 5;  // 0..15
  const int jg = blockIdx.x & 63;
  const int bg = blockIdx.x >> 6;
  const int j0 = jg * 16 + jq * 4;
  const int b = bg * 8 + bl;

  float acc[16];
#pragma unroll
  for (int q = 0; q < 16; ++q) acc[q] = 0.0f;

  const float* hp = hprev + (size_t)b * hp_bs + ks * 64;
  const float* wbase = Wh + (size_t)(ks * 64) * GSZ + j0;
#pragma unroll 4
  for (int k = 0; k < 64; ++k) {
    float s = hp[k];
    const float* wr = wbase + (size_t)k * GSZ;
    float4 w0 = *(const float4*)(wr);
    float4 w1 = *(const float4*)(wr + 1024);
    float4 w2 = *(const float4*)(wr + 2048);
    float4 w3 = *(const float4*)(wr + 3072);
    acc[0] = fmaf(s, w0.x, acc[0]);
    acc[1] = fmaf(s, w0.y, acc[1]);
    acc[2] = fmaf(s, w0.z, acc[2]);
    acc[3] = fmaf(s, w0.w, acc[3]);
    acc[4] = fmaf(s, w1.x, acc[4]);
    acc[5] = fmaf(s, w1.y, acc[5]);
    acc[6] = fmaf(s, w1.z, acc[6]);
    acc[7] = fmaf(s, w1.w, acc[7]);
    acc[8] = fmaf(s, w2.x, acc[8]);
    acc[9] = fmaf(s, w2.y, acc[9]);
    acc[10] = fmaf(s, w2.z, acc[10]);
    acc[11] = fmaf(s, w2.w, acc[11]);
    acc[12] = fmaf(s, w3.x, acc[12]);
    acc[13] = fmaf(s, w3.y, acc[13]);
    acc[14] = fmaf(s, w3.z, acc[14]);
    acc[15] = fmaf(s, w3.w, acc[15]);
  }
#pragma unroll
  for (int q = 0; q < 16; ++q) red[tid][q] = acc[q];
  __syncthreads();
  for (int off = 8; off; off >>= 1) {
    if (ks < off) {
#pragma unroll
      for (int q = 0; q < 16; ++q) {
        acc[q] += red[tid + off * 32][q];
        red[tid][q] = acc[q];
      }
    }
    __syncthreads();
  }
  if (ks == 0) {
    const float* zxr = zx_t + (size_t)b * zx_bs;
    float* crow = c + b * HSZ;
    float* hrow = hout + (size_t)b * ho_bs;
#pragma unroll
    for (int jj = 0; jj < 4; ++jj) {
      int j = j0 + jj;
      float zi = acc[0 + jj] + zxr[j] + bias[j];
      float zj = acc[4 + jj] + zxr[j + 1024] + bias[j + 1024];
      float zf = acc[8 + jj] + zxr[j + 2048] + bias[j + 2048];
      float zo = acc[12 + jj] + zxr[j + 3072] + bias[j + 3072];
      float cold = crow[j];
      float cn = sigf(zf + 1.0f) * cold + sigf(zi) * tanhf(zj);
      float hn = sigf(zo) * tanhf(cn);
      crow[j] = cn;
      hrow[j] = hn;
    }
  }
}

extern "C" void kernel_launch(void* const* d_in, const int* in_sizes, int n_in,
                              void* d_out, int out_size, void* d_ws, size_t ws_size,
                              hipStream_t stream) {
  const float* x  = (const float*)d_in[0];  // [32,256,512]
  const float* W1 = (const float*)d_in[1];  // [1536,4096]
  const float* b1 = (const float*)d_in[2];  // [4096]
  const float* W2 = (const float*)d_in[3];  // [2048,4096]
  const float* b2 = (const float*)d_in[4];  // [4096]
  float* out = (float*)d_out;               // [32,256,1024]

  float* c1    = (float*)d_ws;              // 32*1024
  float* c2    = c1 + BSZ * HSZ;
  float* zeroh = c2 + BSZ * HSZ;            // 32*1024 zeros
  float* H1buf = zeroh + BSZ * HSZ;         // [B,T,H] row-major
  float* ZX    = H1buf + (size_t)BSZ * TSZ * HSZ;  // [B*T,4096]

  // zero c1, c2, zeroh (ws is poisoned before every call)
  hipMemsetAsync(c1, 0, (size_t)3 * BSZ * HSZ * sizeof(float), stream);

  dim3 gemm_grid(GSZ / 128, (BSZ * TSZ) / 128);  // (32, 64)

  // Layer 1: ZX1 = x @ W1[0:512,:]
  sgemm128<<<gemm_grid, 256, 0, stream>>>(x, W1, ZX, BSZ * TSZ, GSZ, DSZ);
  for (int t = 0; t < TSZ; ++t) {
    const float* hp = t ? (H1buf + (size_t)(t - 1) * HSZ) : zeroh;
    long hps = t ? (long)TSZ * HSZ : (long)HSZ;
    lstm_step<<<256, 512, 0, stream>>>(
        W1 + (size_t)DSZ * GSZ,
        ZX + (size_t)t * GSZ, (long)TSZ * GSZ,
        hp, hps, b1, c1,
        H1buf + (size_t)t * HSZ, (long)TSZ * HSZ);
  }

  // Layer 2: ZX2 = h1 @ W2[0:1024,:]  (reuse ZX buffer)
  sgemm128<<<gemm_grid, 256, 0, stream>>>(H1buf, W2, ZX, BSZ * TSZ, GSZ, HSZ);
  for (int t = 0; t < TSZ; ++t) {
    const float* hp = t ? (out + (size_t)(t - 1) * HSZ) : zeroh;
    long hps = t ? (long)TSZ * HSZ : (long)HSZ;
    lstm_step<<<256, 512, 0, stream>>>(
        W2 + (size_t)HSZ * GSZ,
        ZX + (size_t)t * GSZ, (long)TSZ * GSZ,
        hp, hps, b2, c2,
        out + (size_t)t * HSZ, (long)TSZ * HSZ);
  }
}